// Round 11
// baseline (676.005 us; speedup 1.0000x reference)
//
#include <hip/hip_runtime.h>
#include <stdint.h>
#include <stddef.h>

#define TSEQ   2048
#define HDIM   512
#define NHEADS 8
#define HEADD  64
#define NVOCAB 32000
#define NROWS  4096   // B*T

typedef unsigned short ushort_t;
typedef __bf16 bf16x8 __attribute__((ext_vector_type(8)));
typedef float  f32x4  __attribute__((ext_vector_type(4)));
typedef unsigned short us8 __attribute__((ext_vector_type(8)));
typedef unsigned short us4 __attribute__((ext_vector_type(4)));
typedef unsigned short us2 __attribute__((ext_vector_type(2)));

__device__ __forceinline__ ushort_t f2bf(float f){
  union { float f; unsigned int u; } v; v.f = f;
  unsigned int u = v.u;
  u += 0x7FFFu + ((u >> 16) & 1u);   // RNE
  return (ushort_t)(u >> 16);
}

__device__ __forceinline__ void gload_lds16(const ushort_t* g, ushort_t* l){
  __builtin_amdgcn_global_load_lds(
      (const __attribute__((address_space(1))) void*)g,
      (__attribute__((address_space(3))) void*)l, 16, 0, 0);
}

// ---------------- fused f32 -> bf16 convert of all weights + bias concat ----------------
#define CVT_N4   4423680   // 5*65536 + 4096000
#define CVT_TOT  4424064   // + 384
__global__ void cvt_all_kernel(const float* __restrict__ Wprj, const float* __restrict__ Wq,
                               const float* __restrict__ Wk,   const float* __restrict__ Wv,
                               const float* __restrict__ W1,   const float* __restrict__ W2,
                               const float* __restrict__ bq,   const float* __restrict__ bk,
                               const float* __restrict__ bv,
                               ushort_t* __restrict__ wdst, float* __restrict__ bqkv){
  int stride = gridDim.x * blockDim.x;
  for (int i = blockIdx.x * blockDim.x + threadIdx.x; i < CVT_TOT; i += stride){
    if (i < CVT_N4){
      const float* src; int j;
      if (i < 327680){                       // the five 512x512 weights
        int w = i >> 16;                     // 0..4
        j = i & 65535;
        src = (w == 0) ? Wprj : (w == 1) ? Wq : (w == 2) ? Wk : (w == 3) ? Wv : W1;
      } else {
        j = i - 327680;
        src = W2;
      }
      float4 f = ((const float4*)src)[j];
      us4 o;
      o[0] = f2bf(f.x); o[1] = f2bf(f.y); o[2] = f2bf(f.z); o[3] = f2bf(f.w);
      ((us4*)wdst)[i] = o;
    } else {
      int j = i - CVT_N4;                    // 0..383 float4 of bqkv
      const float* src = (j < 128) ? bq : (j < 256) ? bk : bv;
      int jj = j & 127;
      ((float4*)bqkv)[j] = ((const float4*)src)[jj];
    }
  }
}

// ---------------- embedding: x0 = tok[ix] + pos ----------------
__global__ void embed_kernel(const int* __restrict__ ixs, const float* __restrict__ tok,
                             const float* __restrict__ pos, ushort_t* __restrict__ x0){
  const int r = blockIdx.x;            // 0..4095 (b*T + t)
  const int t = r & (TSEQ - 1);
  const int ix = ixs[r];
  const int j = threadIdx.x;           // 0..255, 2 floats each
  const float2 a = ((const float2*)(tok + (size_t)ix * HDIM))[j];
  const float2 p = ((const float2*)(pos + (size_t)t * HDIM))[j];
  us2 o; o[0] = f2bf(a.x + p.x); o[1] = f2bf(a.y + p.y);
  *(us2*)(x0 + (size_t)r * HDIM + j * 2) = o;
}

// ---------------- small GEMM: C[M,N] = A[M,K] @ W[N,K]^T (+bias)(+relu) ----------------
// 128x128 tile, BK=64, double-buffered LDS, XOR chunk swizzle (conflicts=0 per r5).
// MFMA operands SWAPPED (mfma(bfr, af)): lane holds 4 consecutive output columns
// -> vectorized us4/f32x4 epilogue. (Verified r6-r10.)
template<int HAS_BIAS, int RELU, int OUT_F32>
__global__ __launch_bounds__(256) void gemm2_kernel(
    const ushort_t* __restrict__ A, const ushort_t* __restrict__ W,
    const float* __restrict__ bias, void* __restrict__ outp,
    int M, int N, int K)
{
  __shared__ ushort_t As[2][128 * 64];
  __shared__ ushort_t Bs[2][128 * 64];
  const int tid  = threadIdx.x;
  const int wave = tid >> 6;
  const int lane = tid & 63;
  const int lr   = lane & 15;
  const int lg   = lane >> 4;
  const int wr   = wave >> 1, wc = wave & 1;

  const int nwg = gridDim.x;
  const int cpx = nwg >> 3;                    // blocks per XCD chunk
  const int g   = (blockIdx.x & 7) * cpx + (blockIdx.x >> 3);
  const int nby = M >> 7;
  const int by  = g % nby;
  const int bx  = g / nby;
  const int row0 = by << 7;
  const int col0 = bx << 7;

  f32x4 acc[4][4];
#pragma unroll
  for (int m = 0; m < 4; m++)
#pragma unroll
    for (int n = 0; n < 4; n++) acc[m][n] = (f32x4){0.f, 0.f, 0.f, 0.f};

  const int e    = tid * 8;
  const int srow = e >> 6;
  const int gch  = (((e & 63) >> 3) ^ (srow & 7)) * 8;
  const ushort_t* gA = A + (size_t)(row0 + srow) * K + gch;
  const ushort_t* gB = W + (size_t)(col0 + srow) * K + gch;
  const int ldsoff = wave * 512;

#pragma unroll
  for (int p = 0; p < 4; p++){
    gload_lds16(gA + (size_t)(p * 32) * K, &As[0][p * 2048 + ldsoff]);
    gload_lds16(gB + (size_t)(p * 32) * K, &Bs[0][p * 2048 + ldsoff]);
  }
  __syncthreads();

  const int NT = K >> 6;
  for (int t = 0; t < NT; ++t){
    const int cur = t & 1;
    if (t + 1 < NT){
      const int ko = (t + 1) << 6;
#pragma unroll
      for (int p = 0; p < 4; p++){
        gload_lds16(gA + (size_t)(p * 32) * K + ko, &As[cur ^ 1][p * 2048 + ldsoff]);
        gload_lds16(gB + (size_t)(p * 32) * K + ko, &Bs[cur ^ 1][p * 2048 + ldsoff]);
      }
    }
#pragma unroll
    for (int kk = 0; kk < 64; kk += 32){
      const int rch = (((kk >> 3) + lg) ^ (lr & 7)) * 8;   // swizzled read chunk
      bf16x8 af[4], bfr[4];
#pragma unroll
      for (int m = 0; m < 4; m++)
        af[m] = __builtin_bit_cast(bf16x8,
            *(const us8*)&As[cur][(wr * 64 + m * 16 + lr) * 64 + rch]);
#pragma unroll
      for (int n = 0; n < 4; n++)
        bfr[n] = __builtin_bit_cast(bf16x8,
            *(const us8*)&Bs[cur][(wc * 64 + n * 16 + lr) * 64 + rch]);
#pragma unroll
      for (int m = 0; m < 4; m++)
#pragma unroll
        for (int n = 0; n < 4; n++)
          acc[m][n] = __builtin_amdgcn_mfma_f32_16x16x32_bf16(bfr[n], af[m], acc[m][n], 0, 0, 0);
    }
    __syncthreads();
  }

  // epilogue: lane holds rows (wr*64+m*16+lr), cols (wc*64+n*16+lg*4 .. +3)
#pragma unroll
  for (int n = 0; n < 4; n++){
    const int colb = col0 + wc * 64 + n * 16 + lg * 4;
    f32x4 b4 = (f32x4){0.f, 0.f, 0.f, 0.f};
    if (HAS_BIAS) b4 = *(const f32x4*)&bias[colb];
#pragma unroll
    for (int m = 0; m < 4; m++){
      const int row = row0 + wr * 64 + m * 16 + lr;
      float v0 = acc[m][n][0] + b4[0], v1 = acc[m][n][1] + b4[1];
      float v2 = acc[m][n][2] + b4[2], v3 = acc[m][n][3] + b4[3];
      if (RELU){ v0 = fmaxf(v0,0.f); v1 = fmaxf(v1,0.f); v2 = fmaxf(v2,0.f); v3 = fmaxf(v3,0.f); }
      if (OUT_F32){
        f32x4 o = {v0, v1, v2, v3};
        *(f32x4*)&((float*)outp)[(size_t)row * N + colb] = o;
      } else {
        us4 o; o[0] = f2bf(v0); o[1] = f2bf(v1); o[2] = f2bf(v2); o[3] = f2bf(v3);
        *(us4*)&((ushort_t*)outp)[(size_t)row * N + colb] = o;
      }
    }
  }
}

// ---------------- vocab GEMM, W2-panel-resident: out = relu(A @ W2^T + b2), f32 ----------------
// One block per 128-col W2 panel (grid=250). The panel (128x512 bf16 = 128 KB,
// chunk-XOR-swizzled) is staged into LDS ONCE -> W2 HBM traffic = 33 MB total by
// construction (r4-r10 refetched 300-400 MB: the 524 MB write stream cycles L3
// and evicts W2 between re-reads; no schedule can fix an algorithmic re-read).
// A (4 MB, L2-resident) is loaded global->REGISTER per fragment - no LDS, no
// barriers in the main loop. 8 waves (4 row-slices x 2 col-slices, dup=2 -> ~20
// TB/s L2 < 34.5 ceiling), 2 waves/SIMD, register double-buffer a_cur/a_nxt with
// static indices. After the single staging barrier the waves run free - the
// stage->vmcnt(0)->barrier tax (76% idle in r6 PMC) is structurally gone.
// Normal f32x4 stores (NT regressed 16 us in r10 A/B).
__global__ __launch_bounds__(512, 1) void gemm_vocab_kernel(
    const ushort_t* __restrict__ A, const ushort_t* __restrict__ W,
    const float* __restrict__ bias, float* __restrict__ outp)
{
  __shared__ ushort_t Wl[128 * 512];   // 128 KB swizzled panel
  const int K = HDIM, N = NVOCAB;
  const int tid  = threadIdx.x;
  const int wave = tid >> 6;
  const int lane = tid & 63;
  const int lr   = lane & 15;
  const int lg   = lane >> 4;
  const int wr   = wave >> 1;          // 0..3: 32-row A slice
  const int wc   = wave & 1;           // 0..1: 64-col W slice
  const int col0 = blockIdx.x << 7;    // 128-col panel

  // ---- stage panel once: dest chunk d linear; LDS[row][pos] holds global chunk pos^(row&7) ----
#pragma unroll
  for (int pass = 0; pass < 16; ++pass){
    const int d   = pass * 512 + tid;          // 0..8191 chunks
    const int row = d >> 6;                    // 0..127
    const int pos = d & 63;
    const int gck = pos ^ (row & 7);
    gload_lds16(W + (size_t)(col0 + row) * K + gck * 8, &Wl[d * 8]);
  }
  asm volatile("s_waitcnt vmcnt(0)" ::: "memory");
  __syncthreads();
  // no LDS writes after this point -> NO barriers in the main loop.

  // bias for this lane's 2x4 output columns (col-invariant across row-tiles)
  f32x4 b4[4];
#pragma unroll
  for (int n = 0; n < 4; n++) b4[n] = *(const f32x4*)&bias[col0 + wc * 64 + n * 16 + lg * 4];

  for (int rt = 0; rt < 32; ++rt){
    const int row0 = rt << 7;
    const ushort_t* a0 = A + (size_t)(row0 + wr * 32 + lr) * K + lg * 8;

    f32x4 acc[2][4];
#pragma unroll
    for (int m = 0; m < 2; m++)
#pragma unroll
      for (int n = 0; n < 4; n++) acc[m][n] = (f32x4){0.f, 0.f, 0.f, 0.f};

    us8 acur[2][2], anxt[2][2];
#pragma unroll
    for (int m = 0; m < 2; m++)
#pragma unroll
      for (int k2 = 0; k2 < 2; k2++)
        acur[m][k2] = *(const us8*)(a0 + (size_t)m * 16 * K + k2 * 32);

#pragma unroll
    for (int t = 0; t < 8; ++t){
      if (t < 7){
#pragma unroll
        for (int m = 0; m < 2; m++)
#pragma unroll
          for (int k2 = 0; k2 < 2; k2++)
            anxt[m][k2] = *(const us8*)(a0 + (size_t)m * 16 * K + (t + 1) * 64 + k2 * 32);
      }
#pragma unroll
      for (int n = 0; n < 4; n++){
        const int Rw = wc * 64 + n * 16 + lr;
#pragma unroll
        for (int k2 = 0; k2 < 2; k2++){
          const int gc  = t * 8 + k2 * 4 + lg;
          const int pos = gc ^ (Rw & 7);
          bf16x8 wf = __builtin_bit_cast(bf16x8, *(const us8*)&Wl[Rw * 512 + pos * 8]);
#pragma unroll
          for (int m = 0; m < 2; m++)
            acc[m][n] = __builtin_amdgcn_mfma_f32_16x16x32_bf16(
                wf, __builtin_bit_cast(bf16x8, acur[m][k2]), acc[m][n], 0, 0, 0);
        }
      }
      if (t < 7){
#pragma unroll
        for (int m = 0; m < 2; m++)
#pragma unroll
          for (int k2 = 0; k2 < 2; k2++) acur[m][k2] = anxt[m][k2];
      }
    }

    // epilogue: normal f32x4 stores; fire-and-forget, drain under next row-tile
#pragma unroll
    for (int n = 0; n < 4; n++){
      const int colb = col0 + wc * 64 + n * 16 + lg * 4;
#pragma unroll
      for (int m = 0; m < 2; m++){
        const int row = row0 + wr * 32 + m * 16 + lr;
        f32x4 o;
        o[0] = fmaxf(acc[m][n][0] + b4[n][0], 0.f);
        o[1] = fmaxf(acc[m][n][1] + b4[n][1], 0.f);
        o[2] = fmaxf(acc[m][n][2] + b4[n][2], 0.f);
        o[3] = fmaxf(acc[m][n][3] + b4[n][3], 0.f);
        *(f32x4*)&outp[(size_t)row * N + colb] = o;
      }
    }
  }
}

// ---------------- fused causal flash attention ----------------
// Heavy-first dispatch: qt = 31 - blockIdx.x (32:1 causal work spread).
__global__ __launch_bounds__(256) void attn_kernel(
    const ushort_t* __restrict__ qkv, ushort_t* __restrict__ y)
{
  __shared__ ushort_t Ks[64 * 64];
  __shared__ ushort_t Vt[64 * 64];     // transposed: [d][key]
  __shared__ ushort_t Ps[4][16 * 64];
  const int qt   = 31 - blockIdx.x;
  const int hb   = blockIdx.y;
  const int b    = hb >> 3;
  const int h    = hb & 7;
  const int tid  = threadIdx.x;
  const int wave = tid >> 6, lane = tid & 63;
  const int lr   = lane & 15, lg = lane >> 4;
  const int ld   = 3 * HDIM;
  const size_t rowbase = (size_t)b * TSEQ;
  const ushort_t* kb = qkv + HDIM;
  const ushort_t* vb = qkv + 2 * HDIM;

  const int qrow = qt * 64 + wave * 16 + lr;
  const ushort_t* qp = qkv + (rowbase + qrow) * ld + h * HEADD;
  bf16x8 qf[2];
  qf[0] = __builtin_bit_cast(bf16x8, *(const us8*)&qp[lg * 8]);
  qf[1] = __builtin_bit_cast(bf16x8, *(const us8*)&qp[32 + lg * 8]);

  float m_run[4], l_run[4];
  f32x4 acc_o[4];
#pragma unroll
  for (int i = 0; i < 4; i++){ m_run[i] = -1e30f; l_run[i] = 0.f; acc_o[i] = (f32x4){0,0,0,0}; }

  const int e    = tid * 8;
  const int srow = e >> 6;
  const int scol = e & 63;
  const float scale = 0.04419417382415922f;   // 1/sqrt(512) (full H per reference!)

  for (int kt = 0; kt <= qt; ++kt){
    const ushort_t* gK = kb + (rowbase + kt * 64 + srow) * ld + h * HEADD + scol;
    gload_lds16(gK,                     &Ks[wave * 512]);
    gload_lds16(gK + (size_t)32 * ld,   &Ks[2048 + wave * 512]);
    const ushort_t* gV = vb + (rowbase + kt * 64 + srow) * ld + h * HEADD + scol;
    us8 v0 = *(const us8*)gV;
    us8 v1 = *(const us8*)(gV + (size_t)32 * ld);
#pragma unroll
    for (int j = 0; j < 8; j++){
      Vt[(scol + j) * 64 + srow]      = v0[j];
      Vt[(scol + j) * 64 + srow + 32] = v1[j];
    }
    __syncthreads();

    f32x4 s[4];
#pragma unroll
    for (int n = 0; n < 4; n++){
      s[n] = (f32x4){0, 0, 0, 0};
#pragma unroll
      for (int ks = 0; ks < 2; ks++){
        bf16x8 kf = __builtin_bit_cast(bf16x8,
            *(const us8*)&Ks[(n * 16 + lr) * 64 + ks * 32 + lg * 8]);
        s[n] = __builtin_amdgcn_mfma_f32_16x16x32_bf16(qf[ks], kf, s[n], 0, 0, 0);
      }
    }

    float sv[4][4];
    float tmax[4] = {-1e30f, -1e30f, -1e30f, -1e30f};
    const bool diag = (kt == qt);
#pragma unroll
    for (int n = 0; n < 4; n++)
#pragma unroll
      for (int r = 0; r < 4; r++){
        float x = s[n][r] * scale;
        if (diag && (n * 16 + lr) > (wave * 16 + lg * 4 + r)) x = -1e30f;
        sv[n][r] = x;
        tmax[r] = fmaxf(tmax[r], x);
      }
#pragma unroll
    for (int off = 1; off < 16; off <<= 1)
#pragma unroll
      for (int r = 0; r < 4; r++) tmax[r] = fmaxf(tmax[r], __shfl_xor(tmax[r], off));

    float alpha[4], psum[4];
#pragma unroll
    for (int r = 0; r < 4; r++){
      float mn = fmaxf(m_run[r], tmax[r]);
      alpha[r] = __expf(m_run[r] - mn);
      m_run[r] = mn;
      psum[r] = 0.f;
    }
    float p[4][4];
#pragma unroll
    for (int n = 0; n < 4; n++)
#pragma unroll
      for (int r = 0; r < 4; r++){ p[n][r] = __expf(sv[n][r] - m_run[r]); psum[r] += p[n][r]; }
#pragma unroll
    for (int off = 1; off < 16; off <<= 1)
#pragma unroll
      for (int r = 0; r < 4; r++) psum[r] += __shfl_xor(psum[r], off);
#pragma unroll
    for (int r = 0; r < 4; r++) l_run[r] = l_run[r] * alpha[r] + psum[r];
#pragma unroll
    for (int nd = 0; nd < 4; nd++)
#pragma unroll
      for (int r = 0; r < 4; r++) acc_o[nd][r] *= alpha[r];

#pragma unroll
    for (int n = 0; n < 4; n++)
#pragma unroll
      for (int r = 0; r < 4; r++)
        Ps[wave][(lg * 4 + r) * 64 + n * 16 + lr] = f2bf(p[n][r]);
    asm volatile("s_waitcnt lgkmcnt(0)" ::: "memory");
    bf16x8 pa[2];
    pa[0] = __builtin_bit_cast(bf16x8, *(const us8*)&Ps[wave][lr * 64 + lg * 8]);
    pa[1] = __builtin_bit_cast(bf16x8, *(const us8*)&Ps[wave][lr * 64 + 32 + lg * 8]);
#pragma unroll
    for (int nd = 0; nd < 4; nd++)
#pragma unroll
      for (int ks = 0; ks < 2; ks++){
        bf16x8 vf = __builtin_bit_cast(bf16x8,
            *(const us8*)&Vt[(nd * 16 + lr) * 64 + ks * 32 + lg * 8]);
        acc_o[nd] = __builtin_amdgcn_mfma_f32_16x16x32_bf16(pa[ks], vf, acc_o[nd], 0, 0, 0);
      }
    __syncthreads();
  }

  float inv[4];
#pragma unroll
  for (int r = 0; r < 4; r++) inv[r] = 1.f / l_run[r];
#pragma unroll
  for (int nd = 0; nd < 4; nd++)
#pragma unroll
    for (int r = 0; r < 4; r++){
      const int row_t = qt * 64 + wave * 16 + lg * 4 + r;
      y[(rowbase + row_t) * HDIM + h * HEADD + nd * 16 + lr] = f2bf(acc_o[nd][r] * inv[r]);
    }
}

// ---------------- launch ----------------
extern "C" void kernel_launch(void* const* d_in, const int* in_sizes, int n_in,
                              void* d_out, int out_size, void* d_ws, size_t ws_size,
                              hipStream_t stream)
{
  const int*   ixs  = (const int*)  d_in[0];
  const float* tok  = (const float*)d_in[1];
  const float* pos  = (const float*)d_in[2];
  const float* Wprj = (const float*)d_in[3];
  const float* Wq   = (const float*)d_in[4];
  const float* bq_  = (const float*)d_in[5];
  const float* Wk   = (const float*)d_in[6];
  const float* bk_  = (const float*)d_in[7];
  const float* Wv   = (const float*)d_in[8];
  const float* bv_  = (const float*)d_in[9];
  const float* W1   = (const float*)d_in[10];
  const float* b1_  = (const float*)d_in[11];
  const float* W2   = (const float*)d_in[12];
  const float* b2_  = (const float*)d_in[13];
  float* out = (float*)d_out;

  ushort_t* ws    = (ushort_t*)d_ws;
  ushort_t* x0    = ws;                          // 4096*512
  ushort_t* x1    = x0    + 2097152;
  ushort_t* qkv   = x1    + 2097152;             // 4096*1536
  ushort_t* yb    = qkv   + 6291456;
  ushort_t* h1b   = yb    + 2097152;
  ushort_t* wprjb = h1b   + 2097152;             // fused arena [Wprj|Wq|Wk|Wv|W1|W2]
  ushort_t* wqkvb = wprjb + 262144;
  ushort_t* w1b   = wqkvb + 786432;
  ushort_t* w2b   = w1b   + 262144;              // 32000*512
  float*    bqkv  = (float*)(w2b + 16384000);    // 1536 f32

  cvt_all_kernel<<<2048, 256, 0, stream>>>(Wprj, Wq, Wk, Wv, W1, W2,
                                           bq_, bk_, bv_, wprjb, bqkv);

  embed_kernel<<<NROWS, 256, 0, stream>>>(ixs, tok, pos, x0);

  // x1 = x0 @ Wprj^T
  gemm2_kernel<0,0,0><<<32 * 4,   256, 0, stream>>>(x0,  wprjb, nullptr, x1,  NROWS, 512,   512);
  // qkv (fused q|k|v, N=1536)
  gemm2_kernel<1,0,0><<<32 * 12,  256, 0, stream>>>(x1,  wqkvb, bqkv,    qkv, NROWS, 1536,  512);
  // attention
  attn_kernel<<<dim3(32, 16), 256, 0, stream>>>(qkv, yb);
  // h1 = relu(y @ W1^T + b1)
  gemm2_kernel<1,1,0><<<32 * 4,   256, 0, stream>>>(yb,  w1b,   b1_,     h1b, NROWS, 512,   512);
  // out = relu(h1 @ W2^T + b2) -> f32: W2-panel-resident, barrier-free kernel
  gemm_vocab_kernel<<<250, 512, 0, stream>>>(h1b, w2b, b2_, out);
}

// Round 12
// 455.964 us; speedup vs baseline: 1.4826x; 1.4826x over previous
//
#include <hip/hip_runtime.h>
#include <stdint.h>
#include <stddef.h>

#define TSEQ   2048
#define HDIM   512
#define NHEADS 8
#define HEADD  64
#define NVOCAB 32000
#define NROWS  4096   // B*T

typedef unsigned short ushort_t;
typedef __bf16 bf16x8 __attribute__((ext_vector_type(8)));
typedef float  f32x4  __attribute__((ext_vector_type(4)));
typedef unsigned short us8 __attribute__((ext_vector_type(8)));
typedef unsigned short us4 __attribute__((ext_vector_type(4)));
typedef unsigned short us2 __attribute__((ext_vector_type(2)));

__device__ __forceinline__ ushort_t f2bf(float f){
  union { float f; unsigned int u; } v; v.f = f;
  unsigned int u = v.u;
  u += 0x7FFFu + ((u >> 16) & 1u);   // RNE
  return (ushort_t)(u >> 16);
}

__device__ __forceinline__ void gload_lds16(const ushort_t* g, ushort_t* l){
  __builtin_amdgcn_global_load_lds(
      (const __attribute__((address_space(1))) void*)g,
      (__attribute__((address_space(3))) void*)l, 16, 0, 0);
}

// ---------------- fused f32 -> bf16 convert of all weights + bias concat ----------------
#define CVT_N4   4423680   // 5*65536 + 4096000
#define CVT_TOT  4424064   // + 384
__global__ void cvt_all_kernel(const float* __restrict__ Wprj, const float* __restrict__ Wq,
                               const float* __restrict__ Wk,   const float* __restrict__ Wv,
                               const float* __restrict__ W1,   const float* __restrict__ W2,
                               const float* __restrict__ bq,   const float* __restrict__ bk,
                               const float* __restrict__ bv,
                               ushort_t* __restrict__ wdst, float* __restrict__ bqkv){
  int stride = gridDim.x * blockDim.x;
  for (int i = blockIdx.x * blockDim.x + threadIdx.x; i < CVT_TOT; i += stride){
    if (i < CVT_N4){
      const float* src; int j;
      if (i < 327680){                       // the five 512x512 weights
        int w = i >> 16;                     // 0..4
        j = i & 65535;
        src = (w == 0) ? Wprj : (w == 1) ? Wq : (w == 2) ? Wk : (w == 3) ? Wv : W1;
      } else {
        j = i - 327680;
        src = W2;
      }
      float4 f = ((const float4*)src)[j];
      us4 o;
      o[0] = f2bf(f.x); o[1] = f2bf(f.y); o[2] = f2bf(f.z); o[3] = f2bf(f.w);
      ((us4*)wdst)[i] = o;
    } else {
      int j = i - CVT_N4;                    // 0..383 float4 of bqkv
      const float* src = (j < 128) ? bq : (j < 256) ? bk : bv;
      int jj = j & 127;
      ((float4*)bqkv)[j] = ((const float4*)src)[jj];
    }
  }
}

// ---------------- embedding: x0 = tok[ix] + pos ----------------
__global__ void embed_kernel(const int* __restrict__ ixs, const float* __restrict__ tok,
                             const float* __restrict__ pos, ushort_t* __restrict__ x0){
  const int r = blockIdx.x;            // 0..4095 (b*T + t)
  const int t = r & (TSEQ - 1);
  const int ix = ixs[r];
  const int j = threadIdx.x;           // 0..255, 2 floats each
  const float2 a = ((const float2*)(tok + (size_t)ix * HDIM))[j];
  const float2 p = ((const float2*)(pos + (size_t)t * HDIM))[j];
  us2 o; o[0] = f2bf(a.x + p.x); o[1] = f2bf(a.y + p.y);
  *(us2*)(x0 + (size_t)r * HDIM + j * 2) = o;
}

// ---------------- small GEMM: C[M,N] = A[M,K] @ W[N,K]^T (+bias)(+relu) ----------------
// 128x128 tile, BK=64, double-buffered LDS, XOR chunk swizzle (conflicts=0 per r5).
// MFMA operands SWAPPED (mfma(bfr, af)): lane holds 4 consecutive output columns
// -> vectorized us4/f32x4 epilogue. (Verified r6-r11.)
template<int HAS_BIAS, int RELU, int OUT_F32>
__global__ __launch_bounds__(256) void gemm2_kernel(
    const ushort_t* __restrict__ A, const ushort_t* __restrict__ W,
    const float* __restrict__ bias, void* __restrict__ outp,
    int M, int N, int K)
{
  __shared__ ushort_t As[2][128 * 64];
  __shared__ ushort_t Bs[2][128 * 64];
  const int tid  = threadIdx.x;
  const int wave = tid >> 6;
  const int lane = tid & 63;
  const int lr   = lane & 15;
  const int lg   = lane >> 4;
  const int wr   = wave >> 1, wc = wave & 1;

  const int nwg = gridDim.x;
  const int cpx = nwg >> 3;                    // blocks per XCD chunk
  const int g   = (blockIdx.x & 7) * cpx + (blockIdx.x >> 3);
  const int nby = M >> 7;
  const int by  = g % nby;
  const int bx  = g / nby;
  const int row0 = by << 7;
  const int col0 = bx << 7;

  f32x4 acc[4][4];
#pragma unroll
  for (int m = 0; m < 4; m++)
#pragma unroll
    for (int n = 0; n < 4; n++) acc[m][n] = (f32x4){0.f, 0.f, 0.f, 0.f};

  const int e    = tid * 8;
  const int srow = e >> 6;
  const int gch  = (((e & 63) >> 3) ^ (srow & 7)) * 8;
  const ushort_t* gA = A + (size_t)(row0 + srow) * K + gch;
  const ushort_t* gB = W + (size_t)(col0 + srow) * K + gch;
  const int ldsoff = wave * 512;

#pragma unroll
  for (int p = 0; p < 4; p++){
    gload_lds16(gA + (size_t)(p * 32) * K, &As[0][p * 2048 + ldsoff]);
    gload_lds16(gB + (size_t)(p * 32) * K, &Bs[0][p * 2048 + ldsoff]);
  }
  __syncthreads();

  const int NT = K >> 6;
  for (int t = 0; t < NT; ++t){
    const int cur = t & 1;
    if (t + 1 < NT){
      const int ko = (t + 1) << 6;
#pragma unroll
      for (int p = 0; p < 4; p++){
        gload_lds16(gA + (size_t)(p * 32) * K + ko, &As[cur ^ 1][p * 2048 + ldsoff]);
        gload_lds16(gB + (size_t)(p * 32) * K + ko, &Bs[cur ^ 1][p * 2048 + ldsoff]);
      }
    }
#pragma unroll
    for (int kk = 0; kk < 64; kk += 32){
      const int rch = (((kk >> 3) + lg) ^ (lr & 7)) * 8;   // swizzled read chunk
      bf16x8 af[4], bfr[4];
#pragma unroll
      for (int m = 0; m < 4; m++)
        af[m] = __builtin_bit_cast(bf16x8,
            *(const us8*)&As[cur][(wr * 64 + m * 16 + lr) * 64 + rch]);
#pragma unroll
      for (int n = 0; n < 4; n++)
        bfr[n] = __builtin_bit_cast(bf16x8,
            *(const us8*)&Bs[cur][(wc * 64 + n * 16 + lr) * 64 + rch]);
#pragma unroll
      for (int m = 0; m < 4; m++)
#pragma unroll
        for (int n = 0; n < 4; n++)
          acc[m][n] = __builtin_amdgcn_mfma_f32_16x16x32_bf16(bfr[n], af[m], acc[m][n], 0, 0, 0);
    }
    __syncthreads();
  }

  // epilogue: lane holds rows (wr*64+m*16+lr), cols (wc*64+n*16+lg*4 .. +3)
#pragma unroll
  for (int n = 0; n < 4; n++){
    const int colb = col0 + wc * 64 + n * 16 + lg * 4;
    f32x4 b4 = (f32x4){0.f, 0.f, 0.f, 0.f};
    if (HAS_BIAS) b4 = *(const f32x4*)&bias[colb];
#pragma unroll
    for (int m = 0; m < 4; m++){
      const int row = row0 + wr * 64 + m * 16 + lr;
      float v0 = acc[m][n][0] + b4[0], v1 = acc[m][n][1] + b4[1];
      float v2 = acc[m][n][2] + b4[2], v3 = acc[m][n][3] + b4[3];
      if (RELU){ v0 = fmaxf(v0,0.f); v1 = fmaxf(v1,0.f); v2 = fmaxf(v2,0.f); v3 = fmaxf(v3,0.f); }
      if (OUT_F32){
        f32x4 o = {v0, v1, v2, v3};
        *(f32x4*)&((float*)outp)[(size_t)row * N + colb] = o;
      } else {
        us4 o; o[0] = f2bf(v0); o[1] = f2bf(v1); o[2] = f2bf(v2); o[3] = f2bf(v3);
        *(us4*)&((ushort_t*)outp)[(size_t)row * N + colb] = o;
      }
    }
  }
}

// ---------------- vocab GEMM, high-TLP: out = relu(A @ W2^T + b2), f32 ----------------
// Theory (r5-r11 ledger): every vocab variant ran at 2.5-3.8 TB/s effective with
// 1-2 blocks/CU -> the limiter is memory-level parallelism, not the schedule.
// This kernel: 128x128 tile, BK=32 -> only 32 KB LDS, __launch_bounds__(256,4)
// -> 4 blocks/CU (16 waves/CU). Simple stage-next/compute/sync loop; the
// syncthreads drain is hidden by 3 co-resident blocks (m114 TLP overlap).
// Swizzle key (r&3)^((r>>2)&3) on 16B chunks of 32-elem rows -> 2 lanes/bank
// (free, m136); both sides of the involution (pre-swizzled source, swizzled
// read); LDS dest linear. by-inner: 32 consecutive blocks share one W2 panel
// (read ~once via L3); A cycles through L3. Normal f32x4 stores (NT hurt, r10).
__global__ __launch_bounds__(256, 4) void gemm_vocab_kernel(
    const ushort_t* __restrict__ A, const ushort_t* __restrict__ W,
    const float* __restrict__ bias, float* __restrict__ outp)
{
  __shared__ ushort_t As[2][128 * 32];
  __shared__ ushort_t Bs[2][128 * 32];
  const int K = HDIM, N = NVOCAB;
  const int tid  = threadIdx.x;
  const int wave = tid >> 6;
  const int lane = tid & 63;
  const int lr   = lane & 15;
  const int lg   = lane >> 4;
  const int wr   = wave >> 1, wc = wave & 1;
  const int by   = blockIdx.x & 31;     // by-inner: 32 consecutive blocks share a W2 panel
  const int bx   = blockIdx.x >> 5;     // 0..249
  const int row0 = by << 7;
  const int col0 = bx << 7;

  f32x4 acc[4][4];
#pragma unroll
  for (int m = 0; m < 4; m++)
#pragma unroll
    for (int n = 0; n < 4; n++) acc[m][n] = (f32x4){0.f, 0.f, 0.f, 0.f};

  // staging: pass = 64 rows x 32 elems; thread -> row tid>>2, chunk pos tid&3;
  // source chunk = pos ^ key(row), key(r) = (r&3)^((r>>2)&3) (key(r+64)==key(r))
  const int srow = tid >> 2;                                   // 0..63
  const int gch  = ((tid & 3) ^ (srow & 3) ^ ((srow >> 2) & 3)) * 8;
  const ushort_t* gA = A + (size_t)(row0 + srow) * K + gch;
  const ushort_t* gB = W + (size_t)(col0 + srow) * K + gch;
  const int ldsoff = wave * 512;        // linear dest within 2048-elem pass
  // read-side swizzled chunk: frag row = 16-aligned + lr -> key depends only on lr
  const int rch = ((lg ^ (lr & 3) ^ ((lr >> 2) & 3))) * 8;

  // prologue: stage K-tile 0
  gload_lds16(gA,                    &As[0][ldsoff]);
  gload_lds16(gA + (size_t)64 * K,   &As[0][2048 + ldsoff]);
  gload_lds16(gB,                    &Bs[0][ldsoff]);
  gload_lds16(gB + (size_t)64 * K,   &Bs[0][2048 + ldsoff]);
  __syncthreads();

  const int NT = 16;                    // K/32
  for (int t = 0; t < NT; ++t){
    const int cur = t & 1;
    if (t + 1 < NT){
      const int ko = (t + 1) << 5;
      gload_lds16(gA + ko,                  &As[cur ^ 1][ldsoff]);
      gload_lds16(gA + (size_t)64 * K + ko, &As[cur ^ 1][2048 + ldsoff]);
      gload_lds16(gB + ko,                  &Bs[cur ^ 1][ldsoff]);
      gload_lds16(gB + (size_t)64 * K + ko, &Bs[cur ^ 1][2048 + ldsoff]);
    }
    bf16x8 af[4], bfr[4];
#pragma unroll
    for (int m = 0; m < 4; m++)
      af[m] = __builtin_bit_cast(bf16x8,
          *(const us8*)&As[cur][(wr * 64 + m * 16 + lr) * 32 + rch]);
#pragma unroll
    for (int n = 0; n < 4; n++)
      bfr[n] = __builtin_bit_cast(bf16x8,
          *(const us8*)&Bs[cur][(wc * 64 + n * 16 + lr) * 32 + rch]);
#pragma unroll
    for (int m = 0; m < 4; m++)
#pragma unroll
      for (int n = 0; n < 4; n++)
        acc[m][n] = __builtin_amdgcn_mfma_f32_16x16x32_bf16(bfr[n], af[m], acc[m][n], 0, 0, 0);
    __syncthreads();
  }

  // epilogue: lane holds rows (wr*64+m*16+lr), cols (wc*64+n*16+lg*4 .. +3)
#pragma unroll
  for (int n = 0; n < 4; n++){
    const int colb = col0 + wc * 64 + n * 16 + lg * 4;
    const f32x4 b4 = *(const f32x4*)&bias[colb];
#pragma unroll
    for (int m = 0; m < 4; m++){
      const int row = row0 + wr * 64 + m * 16 + lr;
      f32x4 o;
      o[0] = fmaxf(acc[m][n][0] + b4[0], 0.f);
      o[1] = fmaxf(acc[m][n][1] + b4[1], 0.f);
      o[2] = fmaxf(acc[m][n][2] + b4[2], 0.f);
      o[3] = fmaxf(acc[m][n][3] + b4[3], 0.f);
      *(f32x4*)&outp[(size_t)row * N + colb] = o;
    }
  }
}

// ---------------- fused causal flash attention ----------------
// Heavy-first dispatch: qt = 31 - blockIdx.x (32:1 causal work spread).
__global__ __launch_bounds__(256) void attn_kernel(
    const ushort_t* __restrict__ qkv, ushort_t* __restrict__ y)
{
  __shared__ ushort_t Ks[64 * 64];
  __shared__ ushort_t Vt[64 * 64];     // transposed: [d][key]
  __shared__ ushort_t Ps[4][16 * 64];
  const int qt   = 31 - blockIdx.x;
  const int hb   = blockIdx.y;
  const int b    = hb >> 3;
  const int h    = hb & 7;
  const int tid  = threadIdx.x;
  const int wave = tid >> 6, lane = tid & 63;
  const int lr   = lane & 15, lg = lane >> 4;
  const int ld   = 3 * HDIM;
  const size_t rowbase = (size_t)b * TSEQ;
  const ushort_t* kb = qkv + HDIM;
  const ushort_t* vb = qkv + 2 * HDIM;

  const int qrow = qt * 64 + wave * 16 + lr;
  const ushort_t* qp = qkv + (rowbase + qrow) * ld + h * HEADD;
  bf16x8 qf[2];
  qf[0] = __builtin_bit_cast(bf16x8, *(const us8*)&qp[lg * 8]);
  qf[1] = __builtin_bit_cast(bf16x8, *(const us8*)&qp[32 + lg * 8]);

  float m_run[4], l_run[4];
  f32x4 acc_o[4];
#pragma unroll
  for (int i = 0; i < 4; i++){ m_run[i] = -1e30f; l_run[i] = 0.f; acc_o[i] = (f32x4){0,0,0,0}; }

  const int e    = tid * 8;
  const int srow = e >> 6;
  const int scol = e & 63;
  const float scale = 0.04419417382415922f;   // 1/sqrt(512) (full H per reference!)

  for (int kt = 0; kt <= qt; ++kt){
    const ushort_t* gK = kb + (rowbase + kt * 64 + srow) * ld + h * HEADD + scol;
    gload_lds16(gK,                     &Ks[wave * 512]);
    gload_lds16(gK + (size_t)32 * ld,   &Ks[2048 + wave * 512]);
    const ushort_t* gV = vb + (rowbase + kt * 64 + srow) * ld + h * HEADD + scol;
    us8 v0 = *(const us8*)gV;
    us8 v1 = *(const us8*)(gV + (size_t)32 * ld);
#pragma unroll
    for (int j = 0; j < 8; j++){
      Vt[(scol + j) * 64 + srow]      = v0[j];
      Vt[(scol + j) * 64 + srow + 32] = v1[j];
    }
    __syncthreads();

    f32x4 s[4];
#pragma unroll
    for (int n = 0; n < 4; n++){
      s[n] = (f32x4){0, 0, 0, 0};
#pragma unroll
      for (int ks = 0; ks < 2; ks++){
        bf16x8 kf = __builtin_bit_cast(bf16x8,
            *(const us8*)&Ks[(n * 16 + lr) * 64 + ks * 32 + lg * 8]);
        s[n] = __builtin_amdgcn_mfma_f32_16x16x32_bf16(qf[ks], kf, s[n], 0, 0, 0);
      }
    }

    float sv[4][4];
    float tmax[4] = {-1e30f, -1e30f, -1e30f, -1e30f};
    const bool diag = (kt == qt);
#pragma unroll
    for (int n = 0; n < 4; n++)
#pragma unroll
      for (int r = 0; r < 4; r++){
        float x = s[n][r] * scale;
        if (diag && (n * 16 + lr) > (wave * 16 + lg * 4 + r)) x = -1e30f;
        sv[n][r] = x;
        tmax[r] = fmaxf(tmax[r], x);
      }
#pragma unroll
    for (int off = 1; off < 16; off <<= 1)
#pragma unroll
      for (int r = 0; r < 4; r++) tmax[r] = fmaxf(tmax[r], __shfl_xor(tmax[r], off));

    float alpha[4], psum[4];
#pragma unroll
    for (int r = 0; r < 4; r++){
      float mn = fmaxf(m_run[r], tmax[r]);
      alpha[r] = __expf(m_run[r] - mn);
      m_run[r] = mn;
      psum[r] = 0.f;
    }
    float p[4][4];
#pragma unroll
    for (int n = 0; n < 4; n++)
#pragma unroll
      for (int r = 0; r < 4; r++){ p[n][r] = __expf(sv[n][r] - m_run[r]); psum[r] += p[n][r]; }
#pragma unroll
    for (int off = 1; off < 16; off <<= 1)
#pragma unroll
      for (int r = 0; r < 4; r++) psum[r] += __shfl_xor(psum[r], off);
#pragma unroll
    for (int r = 0; r < 4; r++) l_run[r] = l_run[r] * alpha[r] + psum[r];
#pragma unroll
    for (int nd = 0; nd < 4; nd++)
#pragma unroll
      for (int r = 0; r < 4; r++) acc_o[nd][r] *= alpha[r];

#pragma unroll
    for (int n = 0; n < 4; n++)
#pragma unroll
      for (int r = 0; r < 4; r++)
        Ps[wave][(lg * 4 + r) * 64 + n * 16 + lr] = f2bf(p[n][r]);
    asm volatile("s_waitcnt lgkmcnt(0)" ::: "memory");
    bf16x8 pa[2];
    pa[0] = __builtin_bit_cast(bf16x8, *(const us8*)&Ps[wave][lr * 64 + lg * 8]);
    pa[1] = __builtin_bit_cast(bf16x8, *(const us8*)&Ps[wave][lr * 64 + 32 + lg * 8]);
#pragma unroll
    for (int nd = 0; nd < 4; nd++)
#pragma unroll
      for (int ks = 0; ks < 2; ks++){
        bf16x8 vf = __builtin_bit_cast(bf16x8,
            *(const us8*)&Vt[(nd * 16 + lr) * 64 + ks * 32 + lg * 8]);
        acc_o[nd] = __builtin_amdgcn_mfma_f32_16x16x32_bf16(pa[ks], vf, acc_o[nd], 0, 0, 0);
      }
    __syncthreads();
  }

  float inv[4];
#pragma unroll
  for (int r = 0; r < 4; r++) inv[r] = 1.f / l_run[r];
#pragma unroll
  for (int nd = 0; nd < 4; nd++)
#pragma unroll
    for (int r = 0; r < 4; r++){
      const int row_t = qt * 64 + wave * 16 + lg * 4 + r;
      y[(rowbase + row_t) * HDIM + h * HEADD + nd * 16 + lr] = f2bf(acc_o[nd][r] * inv[r]);
    }
}

// ---------------- launch ----------------
extern "C" void kernel_launch(void* const* d_in, const int* in_sizes, int n_in,
                              void* d_out, int out_size, void* d_ws, size_t ws_size,
                              hipStream_t stream)
{
  const int*   ixs  = (const int*)  d_in[0];
  const float* tok  = (const float*)d_in[1];
  const float* pos  = (const float*)d_in[2];
  const float* Wprj = (const float*)d_in[3];
  const float* Wq   = (const float*)d_in[4];
  const float* bq_  = (const float*)d_in[5];
  const float* Wk   = (const float*)d_in[6];
  const float* bk_  = (const float*)d_in[7];
  const float* Wv   = (const float*)d_in[8];
  const float* bv_  = (const float*)d_in[9];
  const float* W1   = (const float*)d_in[10];
  const float* b1_  = (const float*)d_in[11];
  const float* W2   = (const float*)d_in[12];
  const float* b2_  = (const float*)d_in[13];
  float* out = (float*)d_out;

  ushort_t* ws    = (ushort_t*)d_ws;
  ushort_t* x0    = ws;                          // 4096*512
  ushort_t* x1    = x0    + 2097152;
  ushort_t* qkv   = x1    + 2097152;             // 4096*1536
  ushort_t* yb    = qkv   + 6291456;
  ushort_t* h1b   = yb    + 2097152;
  ushort_t* wprjb = h1b   + 2097152;             // fused arena [Wprj|Wq|Wk|Wv|W1|W2]
  ushort_t* wqkvb = wprjb + 262144;
  ushort_t* w1b   = wqkvb + 786432;
  ushort_t* w2b   = w1b   + 262144;              // 32000*512
  float*    bqkv  = (float*)(w2b + 16384000);    // 1536 f32

  cvt_all_kernel<<<2048, 256, 0, stream>>>(Wprj, Wq, Wk, Wv, W1, W2,
                                           bq_, bk_, bv_, wprjb, bqkv);

  embed_kernel<<<NROWS, 256, 0, stream>>>(ixs, tok, pos, x0);

  // x1 = x0 @ Wprj^T
  gemm2_kernel<0,0,0><<<32 * 4,   256, 0, stream>>>(x0,  wprjb, nullptr, x1,  NROWS, 512,   512);
  // qkv (fused q|k|v, N=1536)
  gemm2_kernel<1,0,0><<<32 * 12,  256, 0, stream>>>(x1,  wqkvb, bqkv,    qkv, NROWS, 1536,  512);
  // attention
  attn_kernel<<<dim3(32, 16), 256, 0, stream>>>(qkv, yb);
  // h1 = relu(y @ W1^T + b1)
  gemm2_kernel<1,1,0><<<32 * 4,   256, 0, stream>>>(yb,  w1b,   b1_,     h1b, NROWS, 512,   512);
  // out = relu(h1 @ W2^T + b2) -> f32: high-TLP 128^2/BK=32, 4 blocks/CU
  gemm_vocab_kernel<<<32 * 250, 256, 0, stream>>>(h1b, w2b, b2_, out);
}